// Round 6
// baseline (339.159 us; speedup 1.0000x reference)
//
#include <hip/hip_runtime.h>
#include <stdint.h>

// out[8192,4096] = x[8192,1024] @ W[4096,1024]^T + bias (all fp32; float_quantize
// exp=8/man=23 is an identity). Split-bf16: hi*hi + lo*hi + hi*lo, fp32 MFMA acc.
// Structure: 128x128 tile, 4 waves, 32x32x16 MFMA, BK=16, quad-buffered LDS
// (4x16KB), staged 3 chunks ahead (vmcnt(8) counted), 2 workgroups/CU so one
// wg's LDS-drain/barrier window overlaps the other's MFMA bursts.
#define MM 8192
#define KK 1024
#define NN 4096
#define NCH 64         // K chunks of 16

typedef float f32x16 __attribute__((ext_vector_type(16)));
typedef __bf16 bf16x8 __attribute__((ext_vector_type(8)));
typedef unsigned short u16x8 __attribute__((ext_vector_type(8)));

static __device__ __forceinline__ unsigned short f2bf(float f) {
    unsigned int u = __builtin_bit_cast(unsigned int, f);
    u += 0x7fffu + ((u >> 16) & 1u);    // RNE fp32->bf16 (finite inputs)
    return (unsigned short)(u >> 16);
}
static __device__ __forceinline__ float bf2f(unsigned short s) {
    unsigned int u = ((unsigned int)s) << 16;
    return __builtin_bit_cast(float, u);
}

// ---------------------------------------------------------------------------
// Pack fp32 matrix -> (hi,lo) bf16 planes, tiled 128 rows x 16 k. Per tile:
// [hi 2048 | lo 2048] elems, fragment-contiguous for v_mfma_f32_32x32x16_bf16:
// frag f in [0,4): lane l holds M[bt*128+f*32+(l&31)][kt*16+(l>>5)*8 ..+8]
// (operand layout HW-verified in round 4). One tile = 8KB, staged by 4 gl16.
// ---------------------------------------------------------------------------
__global__ __launch_bounds__(256) void pack_planes(const float* __restrict__ in,
        unsigned short* __restrict__ pk, int total) {
    int i = blockIdx.x * 256 + threadIdx.x;          // octet id
    if (i >= total) return;
    int lane = i & 63, f = (i >> 6) & 3, kt = (i >> 8) & 63, bt = i >> 14;
    int row = bt * 128 + f * 32 + (lane & 31);
    int k   = kt * 16 + (lane >> 5) * 8;
    const float4* s = (const float4*)(in + (size_t)row * KK + k);
    float4 a = s[0], b = s[1];
    float v[8] = {a.x, a.y, a.z, a.w, b.x, b.y, b.z, b.w};
    u16x8 h, l;
#pragma unroll
    for (int j = 0; j < 8; ++j) {
        unsigned short hb = f2bf(v[j]);
        h[j] = hb;
        l[j] = f2bf(v[j] - bf2f(hb));                // exact residual, ~8 more bits
    }
    size_t tb = (size_t)(bt * 64 + kt) * 4096;
    size_t fo = (size_t)f * 512 + lane * 8;
    *(u16x8*)(pk + tb + fo) = h;
    *(u16x8*)(pk + tb + 2048 + fo) = l;
}

static __device__ __forceinline__ bf16x8 ldsr(unsigned addr) {
    bf16x8 r;
    asm volatile("ds_read_b128 %0, %1" : "=v"(r) : "v"(addr));
    return r;
}
static __device__ __forceinline__ void gl16(const unsigned short* g, unsigned short* l) {
    __builtin_amdgcn_global_load_lds(
        (__attribute__((address_space(1))) void*)(void*)g,
        (__attribute__((address_space(3))) void*)(void*)l, 16, 0, 0);
}
static __device__ __forceinline__ void mf(f32x16& d, bf16x8 a, bf16x8 b) {
    d = __builtin_amdgcn_mfma_f32_32x32x16_bf16(a, b, d, 0, 0, 0);
}

// ---------------------------------------------------------------------------
// GEMM: 128x128 wg tile, 4 waves (2Mx2N), per-wave 64x64 = acc[2][2] f32x16.
// Per K16 chunk: 8 ds_read + 4 gl16 (chunk+3) + 12 MFMA + ONE barrier.
// Counted waits only: lgkmcnt(4) (hi frags) then lgkmcnt(0); vmcnt(8) at the
// chunk close (tail: 4/0). No read-phase barrier (CLOSE(ct-1) already orders
// all waves' read-completion before re-staging).
// ---------------------------------------------------------------------------
__global__ __launch_bounds__(256, 2) void qlinear_mfma(
        const unsigned short* __restrict__ Apk, const unsigned short* __restrict__ Bpk,
        const float* __restrict__ bias, float* __restrict__ out) {
    __shared__ __attribute__((aligned(16))) unsigned short S[4][4][2048];  // 64 KB

    // XCD-bijective swizzle (2048 % 8 == 0): XCD c gets wg [c*256,(c+1)*256),
    // covering 16 bm x 16 bn in 4x4 sub-blocks (4 A + 4 B panels = 4MB, L2-fit).
    int bid = blockIdx.x;
    int wg = (bid & 7) * 256 + (bid >> 3);
    int c = wg >> 8, sub = wg & 255;
    int g = sub >> 4, r = sub & 15;
    int bm = (c & 3) * 16 + (g >> 2) * 4 + (r >> 2);   // [0,64)
    int bn = (c >> 2) * 16 + (g & 3) * 4 + (r & 3);    // [0,32)

    const int tid = threadIdx.x;
    const int lane = tid & 63, wid = tid >> 6;
    const int wr = wid >> 1, wc = wid & 1;

    const unsigned lb = (unsigned)(uintptr_t)(__attribute__((address_space(3))) void*)&S[0][0][0];
    const unsigned aA = (unsigned)(wr * 2048 + lane * 16);          // Ah frag base (byte)
    const unsigned aB = (unsigned)(8192 + wc * 2048 + lane * 16);   // Bh frag base

    const size_t abase = (size_t)bm * 262144;   // 64 tiles x 4096 elems
    const size_t bbase = (size_t)bn * 262144;

#define STAGE(T) do {                                                        \
        size_t ta = abase + (size_t)(T) * 4096, tb = bbase + (size_t)(T) * 4096; \
        int bf = (T) & 3;                                                    \
        gl16(Apk + ta + tid * 8,        &S[bf][0][tid * 8]);                 \
        gl16(Apk + ta + 2048 + tid * 8, &S[bf][1][tid * 8]);                 \
        gl16(Bpk + tb + tid * 8,        &S[bf][2][tid * 8]);                 \
        gl16(Bpk + tb + 2048 + tid * 8, &S[bf][3][tid * 8]);                 \
    } while (0)

    f32x16 acc[2][2];
#pragma unroll
    for (int mi = 0; mi < 2; ++mi)
#pragma unroll
        for (int ni = 0; ni < 2; ++ni)
#pragma unroll
            for (int q = 0; q < 16; ++q) acc[mi][ni][q] = 0.f;

    // prologue: stage chunks 0,1,2 (12 loads); need chunk 0 -> vmcnt(8)
    STAGE(0); STAGE(1); STAGE(2);
    asm volatile("s_waitcnt vmcnt(8)" ::: "memory");
    __builtin_amdgcn_s_barrier();

    for (int ct = 0; ct < NCH; ++ct) {
        const unsigned cb = lb + (unsigned)(ct & 3) * 16384u;
        // reads ordered: hi frags first (lgkmcnt(4) releases them early)
        bf16x8 Ah0 = ldsr(cb + aA);
        bf16x8 Ah1 = ldsr(cb + aA + 1024u);
        bf16x8 Bh0 = ldsr(cb + aB);
        bf16x8 Bh1 = ldsr(cb + aB + 1024u);
        bf16x8 Al0 = ldsr(cb + aA + 4096u);
        bf16x8 Al1 = ldsr(cb + aA + 5120u);
        bf16x8 Bl0 = ldsr(cb + aB + 4096u);
        bf16x8 Bl1 = ldsr(cb + aB + 5120u);
        if (ct < NCH - 3) STAGE(ct + 3);

        asm volatile("s_waitcnt lgkmcnt(4)" ::: "memory");   // hi frags landed
        __builtin_amdgcn_sched_barrier(0);
        __builtin_amdgcn_s_setprio(1);
        mf(acc[0][0], Ah0, Bh0); mf(acc[0][1], Ah0, Bh1);
        mf(acc[1][0], Ah1, Bh0); mf(acc[1][1], Ah1, Bh1);
        asm volatile("s_waitcnt lgkmcnt(0)" ::: "memory");   // lo frags landed
        __builtin_amdgcn_sched_barrier(0);
        mf(acc[0][0], Al0, Bh0); mf(acc[0][1], Al0, Bh1);
        mf(acc[1][0], Al1, Bh0); mf(acc[1][1], Al1, Bh1);
        mf(acc[0][0], Ah0, Bl0); mf(acc[0][1], Ah0, Bl1);
        mf(acc[1][0], Ah1, Bl0); mf(acc[1][1], Ah1, Bl1);
        __builtin_amdgcn_s_setprio(0);
        __builtin_amdgcn_sched_barrier(0);

        // close: ensure chunk ct+1's planes (oldest 4 in flight) have landed
        if (ct <= NCH - 4)      { asm volatile("s_waitcnt vmcnt(8)" ::: "memory"); }
        else if (ct == NCH - 3) { asm volatile("s_waitcnt vmcnt(4)" ::: "memory"); }
        else if (ct == NCH - 2) { asm volatile("s_waitcnt vmcnt(0)" ::: "memory"); }
        __builtin_amdgcn_s_barrier();
    }
#undef STAGE

    // epilogue: 32x32 C/D layout col=lane&31, row=(r&3)+8*(r>>2)+4*(lane>>5)
    // (HW-verified in round 4)
    const int row0 = bm * 128 + wr * 64 + 4 * (lane >> 5);
    const int col0 = bn * 128 + wc * 64 + (lane & 31);
    float bv[2] = {bias[col0], bias[col0 + 32]};
#pragma unroll
    for (int mi = 0; mi < 2; ++mi)
#pragma unroll
        for (int ni = 0; ni < 2; ++ni)
#pragma unroll
            for (int q = 0; q < 16; ++q) {
                int rr = row0 + mi * 32 + (q & 3) + 8 * (q >> 2);
                out[(size_t)rr * NN + col0 + ni * 32] = acc[mi][ni][q] + bv[ni];
            }
}

// ---------------------------------------------------------------------------
// Fallback (ws too small): naive fp32 GEMM.
// ---------------------------------------------------------------------------
__global__ __launch_bounds__(256) void qlinear_naive(const float* __restrict__ x,
                                                     const float* __restrict__ w,
                                                     const float* __restrict__ bias,
                                                     float* __restrict__ out) {
    int n = blockIdx.x * 64 + (threadIdx.x & 63);
    int m = blockIdx.y * 4 + (threadIdx.x >> 6);
    const float4* xr = (const float4*)(x + (size_t)m * KK);
    const float4* wr = (const float4*)(w + (size_t)n * KK);
    float s = 0.f;
    for (int k = 0; k < KK / 4; ++k) {
        float4 a = xr[k], b = wr[k];
        s += a.x * b.x + a.y * b.y + a.z * b.z + a.w * b.w;
    }
    out[(size_t)m * NN + n] = s + bias[n];
}

extern "C" void kernel_launch(void* const* d_in, const int* in_sizes, int n_in,
                              void* d_out, int out_size, void* d_ws, size_t ws_size,
                              hipStream_t stream) {
    (void)in_sizes; (void)n_in; (void)out_size;
    const float* x = (const float*)d_in[0];
    const float* w = (const float*)d_in[1];
    const float* bias = (const float*)d_in[2];
    float* out = (float*)d_out;

    const size_t xcnt = (size_t)MM * KK;   // 8,388,608
    const size_t wcnt = (size_t)NN * KK;   // 4,194,304
    const size_t need = (2 * xcnt + 2 * wcnt) * sizeof(unsigned short);  // 48 MiB

    if (ws_size >= need) {
        unsigned short* Apk = (unsigned short*)d_ws;   // 2*xcnt elems
        unsigned short* Bpk = Apk + 2 * xcnt;          // 2*wcnt elems
        pack_planes<<<(int)(xcnt / 8 / 256), 256, 0, stream>>>(x, Apk, (int)(xcnt / 8));
        pack_planes<<<(int)(wcnt / 8 / 256), 256, 0, stream>>>(w, Bpk, (int)(wcnt / 8));
        qlinear_mfma<<<2048, 256, 0, stream>>>(Apk, Bpk, bias, out);
    } else {
        dim3 grid(NN / 64, MM / 4);
        qlinear_naive<<<grid, 256, 0, stream>>>(x, w, bias, out);
    }
}